// Round 13
// baseline (622.249 us; speedup 1.0000x reference)
//
#include <hip/hip_runtime.h>
#include <hip/hip_bf16.h>

typedef __bf16 bf16_t;
typedef __bf16 bf16x8 __attribute__((ext_vector_type(8)));
typedef __bf16 bf16x4 __attribute__((ext_vector_type(4)));
typedef float f32x4 __attribute__((ext_vector_type(4)));
typedef float f32x16 __attribute__((ext_vector_type(16)));
typedef unsigned int u32x4 __attribute__((ext_vector_type(4)));

#define AS1(p) ((const __attribute__((address_space(1))) void*)(p))
#define AS3(p) ((__attribute__((address_space(3))) void*)(p))

// scale = HEAD_DIM^-0.5 * log2(e), folded into Q at QKV-GEMM epilogue
#define QSCALE 0.1803368801111204f

// ---------------- fused prep: cast X + transpose/cast both W (one launch) ----------------
__global__ __launch_bounds__(256) void prep_kernel(
    const float* __restrict__ X, bf16_t* __restrict__ Xb,
    const float* __restrict__ Wqkv, bf16_t* __restrict__ Wqkvt,
    const float* __restrict__ Wout, bf16_t* __restrict__ Woutt) {
  __shared__ float tile[32][33];
  int bid = blockIdx.x;
  if (bid < 8192) {
    int i = (bid * 256 + threadIdx.x) * 4;
    float4 v = *(const float4*)(X + i);
    bf16x4 o;
    o[0] = (bf16_t)v.x; o[1] = (bf16_t)v.y; o[2] = (bf16_t)v.z; o[3] = (bf16_t)v.w;
    *(bf16x4*)(Xb + i) = o;
    return;
  }
  bid -= 8192;
  const float* W; bf16_t* Wt; int N, bx, by;
  if (bid < 3072) { W = Wqkv; Wt = Wqkvt; N = 3072; bx = bid % 96; by = bid / 96; }
  else { bid -= 3072; W = Wout; Wt = Woutt; N = 1024; bx = bid & 31; by = bid >> 5; }
  const int K = 1024;
  int tx = threadIdx.x & 31, ty = threadIdx.x >> 5;
  int n0 = bx * 32, k0 = by * 32;
  for (int r = ty; r < 32; r += 8)
    tile[r][tx] = W[(size_t)(k0 + r) * N + n0 + tx];
  __syncthreads();
  for (int r = ty; r < 32; r += 8)
    Wt[(size_t)(n0 + r) * K + k0 + tx] = (bf16_t)tile[tx][r];
}

// ---------------- QKV GEMM: C[8192,3072] = Xb[8192,1024] @ Wt[3072,1024]^T ----------------
// BK=64, swizzled staging (rule #21), XCD-band swizzle. r12-measured structure.
__global__ __launch_bounds__(256) void gemm_qkv_kernel(
    const bf16_t* __restrict__ A, const bf16_t* __restrict__ Bt,
    bf16_t* __restrict__ Qb, bf16_t* __restrict__ Kb, bf16_t* __restrict__ Vt) {
  __shared__ __align__(16) bf16_t As[128 * 64];
  __shared__ __align__(16) bf16_t Bs[128 * 64];
  const int tid = threadIdx.x;
  const int lane = tid & 63, wave = tid >> 6;
  const int quad = lane >> 4, l15 = lane & 15;
  const int wr = wave >> 1, wc = wave & 1;
  const int bid = blockIdx.x;
  const int mt_ = (bid & 7) * 8 + ((bid >> 3) & 7);  // m-tile 0..63
  const int nt_ = bid >> 6;                          // n-tile 0..23
  const int m0 = mt_ * 128, n0 = nt_ * 128;
  f32x4 acc[4][4];
  const f32x4 vzero = {0.f, 0.f, 0.f, 0.f};
#pragma unroll
  for (int i = 0; i < 4; i++)
#pragma unroll
    for (int j = 0; j < 4; j++) acc[i][j] = vzero;

  for (int kb = 0; kb < 1024; kb += 64) {
    __syncthreads();
#pragma unroll
    for (int i = 0; i < 4; i++) {
      int slot = i * 256 + tid;                 // 1024 slots x 16B = 128 rows x 64 k
      int row = slot >> 3, ch = slot & 7;
      int gch = ch ^ (row & 7);                 // pre-swizzled global chunk
      __builtin_amdgcn_global_load_lds(AS1(A + (size_t)(m0 + row) * 1024 + kb + gch * 8),
                                       AS3(As + slot * 8), 16, 0, 0);
    }
#pragma unroll
    for (int i = 0; i < 4; i++) {
      int slot = i * 256 + tid;
      int row = slot >> 3, ch = slot & 7;
      int gch = ch ^ (row & 7);
      __builtin_amdgcn_global_load_lds(AS1(Bt + (size_t)(n0 + row) * 1024 + kb + gch * 8),
                                       AS3(Bs + slot * 8), 16, 0, 0);
    }
    __builtin_amdgcn_s_waitcnt(0);
    __syncthreads();
#pragma unroll
    for (int ks = 0; ks < 2; ks++) {            // two 32-wide K-substeps
      bf16x8 af[4], bfr[4];
#pragma unroll
      for (int t = 0; t < 4; t++) {
        int ra = wr * 64 + t * 16 + l15;
        af[t]  = *(const bf16x8*)(As + ra * 64 + ((ks * 4 + quad) ^ (ra & 7)) * 8);
        int rb = wc * 64 + t * 16 + l15;
        bfr[t] = *(const bf16x8*)(Bs + rb * 64 + ((ks * 4 + quad) ^ (rb & 7)) * 8);
      }
#pragma unroll
      for (int mt = 0; mt < 4; mt++)
#pragma unroll
        for (int nt = 0; nt < 4; nt++)
          acc[mt][nt] = __builtin_amdgcn_mfma_f32_16x16x32_bf16(af[mt], bfr[nt], acc[mt][nt], 0, 0, 0);
    }
  }
  // C layout: col=lane&15, row=quad*4+reg
#pragma unroll
  for (int nt = 0; nt < 4; nt++) {
    int gn = n0 + wc * 64 + nt * 16 + l15;
    int which = gn >> 10;   // 0=Q, 1=K, 2=V (uniform across lanes per nt)
    int rem = gn & 1023;
    int hh = rem >> 6, dd = rem & 63;
    if (which == 2) {
      // V transposed: Vt[b][h][dd][s], r-dim is consecutive s -> 8B vector store
#pragma unroll
      for (int mt = 0; mt < 4; mt++) {
        int gm0 = m0 + wr * 64 + mt * 16 + quad * 4;
        int b = gm0 >> 11, s = gm0 & 2047;
        bf16x4 o;
#pragma unroll
        for (int r = 0; r < 4; r++) o[r] = (bf16_t)acc[mt][nt][r];
        *(bf16x4*)(Vt + ((size_t)((b << 4) + hh) * 64 + dd) * 2048 + s) = o;
      }
    } else {
      bf16_t* dst = (which == 0) ? Qb : Kb;
      float scl = (which == 0) ? QSCALE : 1.0f;
#pragma unroll
      for (int mt = 0; mt < 4; mt++) {
#pragma unroll
        for (int r = 0; r < 4; r++) {
          int gm = m0 + wr * 64 + mt * 16 + quad * 4 + r;
          int b = gm >> 11, s = gm & 2047;
          dst[((size_t)((b << 4) + hh) * 2048 + s) * 64 + dd] = (bf16_t)(acc[mt][nt][r] * scl);
        }
      }
    }
  }
}

// pack two f32 into one u32 of 2 bf16
__device__ inline unsigned pack_bf16x2(float a, float b) {
  unsigned short lo = __builtin_bit_cast(unsigned short, (bf16_t)a);
  unsigned short hi = __builtin_bit_cast(unsigned short, (bf16_t)b);
  return (unsigned)lo | ((unsigned)hi << 16);
}

// ---------------- Flash attention, causal, no-max softmax, UNIFORM-LENGTH blocks ----------
// Wall model M (r2/r4/r6 evidence): wall = longest block's body count x ~0.30us.
// Fix: pair (p, P=15-p) and split into two 17-iter blocks with EXACTLY equal
// per-wave body counts (31+w each):
//   A (ab=0): tile p fully (incl diag, ctx direct) + first m=15-2p iters of tile P
//             (provably mask-free) -> partial (PA, LA) f32.
//   B (ab=1): tile P iters m..2P+1 (incl diag) -> partial (PB, LB).
// No-max exp2 softmax => partials combine EXACTLY by addition (normalize kernel).
// Datapath byte-identical to r8/r11 (sigma QK^T, scalar L, split 2-chains); no new
// live f32x16 (accumulators reused sequentially) -> no r5/r10 spill hazard.
__global__ __launch_bounds__(256, 4) void attn_kernel(
    const bf16_t* __restrict__ Qg_, const bf16_t* __restrict__ Kg_,
    const bf16_t* __restrict__ Vtg_, bf16_t* __restrict__ ctx,
    float* __restrict__ PA, float* __restrict__ PB,
    float* __restrict__ LA, float* __restrict__ LB) {
  __shared__ __align__(16) bf16_t Ksm[2][64 * 64];  // [k][d], 16B slots XOR row&7
  __shared__ __align__(16) bf16_t Vsm[2][64 * 64];  // [d][s], 16B slots XOR d&7
  __shared__ float Lsh[128];
  const int tid = threadIdx.x;
  const int lane = tid & 63, w = tid >> 6;
  const int l31 = lane & 31, hl = lane >> 5;
  const int krow = (l31 & 0x13) | ((l31 & 4) << 1) | ((l31 & 8) >> 1);

  const int bh = blockIdx.x & 63;            // low bits -> XCD = bh%8
  const int pp = (blockIdx.x >> 6) & 7;      // pair index
  const int ab = blockIdx.x >> 9;            // 0=A, 1=B
  const int p = pp, Pq = 15 - pp;
  const int Jp = 2 * (p + 1);                // iters of tile p
  const int mA = 15 - 2 * p;                 // A's mask-free prefix on tile P (17-Jp)
  const int b = bh >> 4, h = bh & 15;
  const size_t base = (size_t)bh * 2048 * 64;
  const bf16_t* Qg = Qg_ + base;
  const bf16_t* Kg = Kg_ + base;
  const bf16_t* Vtg = Vtg_ + base;           // [d][s]

  int kadr[4];
#pragma unroll
  for (int kk = 0; kk < 4; kk++)
    kadr[kk] = (krow * 8 + ((kk * 2 + hl) ^ (krow & 7))) * 8;
  int vadr[2];
#pragma unroll
  for (int nv = 0; nv < 2; nv++) {
    const int dr = nv * 32 + l31;
    vadr[nv] = (dr * 8 + (hl ^ (dr & 7))) * 8;
  }

  auto stage_kv = [&](int bb, int jn) {
#pragma unroll
    for (int i = 0; i < 2; i++) {
      int slot = i * 256 + tid;
      int row = slot >> 3, c = (slot & 7) ^ (row & 7);
      __builtin_amdgcn_global_load_lds(AS1(Kg + ((size_t)jn * 64 + row) * 64 + c * 8),
                                       AS3(&Ksm[bb][0] + slot * 8), 16, 0, 0);
    }
#pragma unroll
    for (int i = 0; i < 2; i++) {
      int slot = i * 256 + tid;
      int d = slot >> 3, c = (slot & 7) ^ (d & 7);
      __builtin_amdgcn_global_load_lds(AS1(Vtg + (size_t)d * 2048 + jn * 64 + c * 8),
                                       AS3(&Vsm[bb][0] + slot * 8), 16, 0, 0);
    }
  };

  f32x16 zc;
#pragma unroll
  for (int e = 0; e < 16; e++) zc[e] = 0.f;

  const int tix = bh * 8 + pp;
  float* Pp = (ab ? PB : PA) + (size_t)tix * (128 * 64);
  float* Lp = (ab ? LB : LA) + tix * 128;

  int qrel = (ab ? Pq : p) * 128 + w * 32;   // current tile's wave q-base
  bf16x8 aq[4];
  auto load_aq = [&](int qb_) {
    const int qgl = qb_ * 128 + w * 32 + l31;
#pragma unroll
    for (int kk = 0; kk < 4; kk++)
      aq[kk] = *(const bf16x8*)(Qg + (size_t)qgl * 64 + kk * 16 + hl * 8);
  };
  load_aq(ab ? Pq : p);

  f32x16 Oacc[2];
#pragma unroll
  for (int e = 0; e < 16; e++) { Oacc[0][e] = 0.f; Oacc[1][e] = 0.f; }
  float Lpart = 0.f;

  int cur = 0;
  stage_kv(0, ab ? mA : 0);

  for (int i = 0; i < 17; ++i) {
    asm volatile("s_waitcnt vmcnt(0)" ::: "memory");
    __syncthreads();
    if (i + 1 < 17) {
      const int ni = i + 1;
      const int nj = ab ? (mA + ni) : (ni < Jp ? ni : ni - Jp);
      stage_kv(cur ^ 1, nj);
    }
    const bf16_t* Kb = &Ksm[cur][0];
    const bf16_t* Vb = &Vsm[cur][0];
    const int j = ab ? (mA + i) : (i < Jp ? i : i - Jp);
    const int k0 = j * 64;

    auto nt_body = [&](int nt, bool masked) {
      __builtin_amdgcn_s_setprio(1);
      bf16x8 a0 = *(const bf16x8*)(Kb + nt * 2048 + kadr[0]);
      bf16x8 a1 = *(const bf16x8*)(Kb + nt * 2048 + kadr[1]);
      f32x16 sa = __builtin_amdgcn_mfma_f32_32x32x16_bf16(a0, aq[0], zc, 0, 0, 0);
      f32x16 sb = __builtin_amdgcn_mfma_f32_32x32x16_bf16(a1, aq[1], zc, 0, 0, 0);
      bf16x8 a2 = *(const bf16x8*)(Kb + nt * 2048 + kadr[2]);
      bf16x8 a3 = *(const bf16x8*)(Kb + nt * 2048 + kadr[3]);
      sa = __builtin_amdgcn_mfma_f32_32x32x16_bf16(a2, aq[2], sa, 0, 0, 0);
      sb = __builtin_amdgcn_mfma_f32_32x32x16_bf16(a3, aq[3], sb, 0, 0, 0);
      __builtin_amdgcn_s_setprio(0);

      float p16[16];
#pragma unroll
      for (int r = 0; r < 16; r++) {
        const int koff = hl * 8 + (r & 7) + 16 * (r >> 3);
        const float x = sa[r] + sb[r];
        p16[r] = (masked && (koff > l31)) ? 0.f : __builtin_exp2f(x);
      }
      {
        float a0s = p16[0] + p16[1], a1s = p16[2] + p16[3];
        float a2s = p16[4] + p16[5], a3s = p16[6] + p16[7];
        float a4s = p16[8] + p16[9], a5s = p16[10] + p16[11];
        float a6s = p16[12] + p16[13], a7s = p16[14] + p16[15];
        Lpart += ((a0s + a1s) + (a2s + a3s)) + ((a4s + a5s) + (a6s + a7s));
      }
      u32x4 w0, w1;
      w0[0] = pack_bf16x2(p16[0], p16[1]);   w0[1] = pack_bf16x2(p16[2], p16[3]);
      w0[2] = pack_bf16x2(p16[4], p16[5]);   w0[3] = pack_bf16x2(p16[6], p16[7]);
      w1[0] = pack_bf16x2(p16[8], p16[9]);   w1[1] = pack_bf16x2(p16[10], p16[11]);
      w1[2] = pack_bf16x2(p16[12], p16[13]); w1[3] = pack_bf16x2(p16[14], p16[15]);
      bf16x8 pa0 = __builtin_bit_cast(bf16x8, w0);
      bf16x8 pa1 = __builtin_bit_cast(bf16x8, w1);

      __builtin_amdgcn_s_setprio(1);
#pragma unroll
      for (int nv = 0; nv < 2; nv++) {
        bf16x8 bv0 = *(const bf16x8*)(Vb + (vadr[nv] ^ ((nt * 4 + 0) * 8)));
        Oacc[nv] = __builtin_amdgcn_mfma_f32_32x32x16_bf16(pa0, bv0, Oacc[nv], 0, 0, 0);
        bf16x8 bv1 = *(const bf16x8*)(Vb + (vadr[nv] ^ ((nt * 4 + 2) * 8)));
        Oacc[nv] = __builtin_amdgcn_mfma_f32_32x32x16_bf16(pa1, bv1, Oacc[nv], 0, 0, 0);
      }
      __builtin_amdgcn_s_setprio(0);
    };

    if (!ab && i >= Jp) {
      // A's tile-P prefix: always active, never masked (k0 < qrel_P for all waves)
      nt_body(0, false);
      nt_body(1, false);
    } else {
#pragma unroll
      for (int nt = 0; nt < 2; nt++) {
        const int kk0 = k0 + nt * 32;
        if (kk0 <= qrel) nt_body(nt, kk0 == qrel);
      }
    }

    if (!ab && i == Jp - 1) {
      // tile-p complete: direct ctx epilogue, then switch state to tile P
      float Lf = Lpart + __shfl_xor(Lpart, 32, 64);
      if (hl == 0) Lsh[w * 32 + l31] = Lf;
      asm volatile("s_waitcnt lgkmcnt(0)" ::: "memory");
#pragma unroll
      for (int r = 0; r < 16; r++) {
        const int crow = (r & 3) + 8 * (r >> 2) + 4 * hl;
        const float rl = __builtin_amdgcn_rcpf(Lsh[w * 32 + crow]);
        const int qrow = p * 128 + w * 32 + crow;
#pragma unroll
        for (int nv = 0; nv < 2; nv++)
          ctx[((size_t)b * 2048 + qrow) * 1024 + h * 64 + nv * 32 + l31] =
              (bf16_t)(Oacc[nv][r] * rl);
      }
#pragma unroll
      for (int e = 0; e < 16; e++) { Oacc[0][e] = 0.f; Oacc[1][e] = 0.f; }
      Lpart = 0.f;
      load_aq(Pq);
      qrel = Pq * 128 + w * 32;
    }
    cur ^= 1;
  }

  // write tile-P partial (A: prefix; B: suffix). Combine is exact (no-max softmax).
  float Lf = Lpart + __shfl_xor(Lpart, 32, 64);
  if (hl == 0) Lp[w * 32 + l31] = Lf;
#pragma unroll
  for (int r = 0; r < 16; r++) {
    const int crow = (r & 3) + 8 * (r >> 2) + 4 * hl;
    const int row = w * 32 + crow;
#pragma unroll
    for (int nv = 0; nv < 2; nv++)
      Pp[row * 64 + nv * 32 + l31] = Oacc[nv][r];
  }
}

// ---------------- combine partials -> ctx upper tiles ----------------
__global__ __launch_bounds__(256) void attn_norm_kernel(
    const float* __restrict__ PA, const float* __restrict__ PB,
    const float* __restrict__ LA, const float* __restrict__ LB,
    bf16_t* __restrict__ ctx) {
  const int t = blockIdx.x;            // 0..511 = bh*8 + pp
  const int bh = t >> 3, pp = t & 7;
  const int Pq = 15 - pp;
  const int b = bh >> 4, h = bh & 15;
  const float4* pa = (const float4*)(PA + (size_t)t * 8192);
  const float4* pb = (const float4*)(PB + (size_t)t * 8192);
  const float* la = LA + t * 128;
  const float* lb = LB + t * 128;
#pragma unroll
  for (int k = 0; k < 8; k++) {
    const int v = threadIdx.x + k * 256;   // 0..2047 float4 index (16 per row)
    const int row = v >> 4, dd = (v & 15) * 4;
    float4 a = pa[v], c = pb[v];
    const float rl = __builtin_amdgcn_rcpf(la[row] + lb[row]);
    bf16x4 o;
    o[0] = (bf16_t)((a.x + c.x) * rl);
    o[1] = (bf16_t)((a.y + c.y) * rl);
    o[2] = (bf16_t)((a.z + c.z) * rl);
    o[3] = (bf16_t)((a.w + c.w) * rl);
    *(bf16x4*)(ctx + ((size_t)b * 2048 + Pq * 128 + row) * 1024 + h * 64 + dd) = o;
  }
}

// ---------------- out proj: out[8192,1024] = ctx @ Wout^T + b ----------------
__global__ __launch_bounds__(256) void gemm_out_kernel(
    const bf16_t* __restrict__ A, const bf16_t* __restrict__ Bt,
    const float* __restrict__ bias, float* __restrict__ out) {
  __shared__ __align__(16) bf16_t As[128 * 64];
  __shared__ __align__(16) bf16_t Bs[128 * 64];
  const int tid = threadIdx.x;
  const int lane = tid & 63, wave = tid >> 6;
  const int quad = lane >> 4, l15 = lane & 15;
  const int wr = wave >> 1, wc = wave & 1;
  const int bid = blockIdx.x;
  const int mt_ = (bid & 7) * 8 + ((bid >> 3) & 7);  // m-tile 0..63
  const int nt_ = bid >> 6;                          // n-tile 0..7
  const int m0 = mt_ * 128, n0 = nt_ * 128;
  f32x4 acc[4][4];
  const f32x4 vzero = {0.f, 0.f, 0.f, 0.f};
#pragma unroll
  for (int i = 0; i < 4; i++)
#pragma unroll
    for (int j = 0; j < 4; j++) acc[i][j] = vzero;

  for (int kb = 0; kb < 1024; kb += 64) {
    __syncthreads();
#pragma unroll
    for (int i = 0; i < 4; i++) {
      int slot = i * 256 + tid;
      int row = slot >> 3, ch = slot & 7;
      int gch = ch ^ (row & 7);
      __builtin_amdgcn_global_load_lds(AS1(A + (size_t)(m0 + row) * 1024 + kb + gch * 8),
                                       AS3(As + slot * 8), 16, 0, 0);
    }
#pragma unroll
    for (int i = 0; i < 4; i++) {
      int slot = i * 256 + tid;
      int row = slot >> 3, ch = slot & 7;
      int gch = ch ^ (row & 7);
      __builtin_amdgcn_global_load_lds(AS1(Bt + (size_t)(n0 + row) * 1024 + kb + gch * 8),
                                       AS3(Bs + slot * 8), 16, 0, 0);
    }
    __builtin_amdgcn_s_waitcnt(0);
    __syncthreads();
#pragma unroll
    for (int ks = 0; ks < 2; ks++) {
      bf16x8 af[4], bfr[4];
#pragma unroll
      for (int t = 0; t < 4; t++) {
        int ra = wr * 64 + t * 16 + l15;
        af[t]  = *(const bf16x8*)(As + ra * 64 + ((ks * 4 + quad) ^ (ra & 7)) * 8);
        int rb = wc * 64 + t * 16 + l15;
        bfr[t] = *(const bf16x8*)(Bs + rb * 64 + ((ks * 4 + quad) ^ (rb & 7)) * 8);
      }
#pragma unroll
      for (int mt = 0; mt < 4; mt++)
#pragma unroll
        for (int nt = 0; nt < 4; nt++)
          acc[mt][nt] = __builtin_amdgcn_mfma_f32_16x16x32_bf16(af[mt], bfr[nt], acc[mt][nt], 0, 0, 0);
    }
  }
#pragma unroll
  for (int nt = 0; nt < 4; nt++) {
    int gn = n0 + wc * 64 + nt * 16 + l15;
    float bv = bias[gn];
#pragma unroll
    for (int mt = 0; mt < 4; mt++) {
#pragma unroll
      for (int r = 0; r < 4; r++) {
        int gm = m0 + wr * 64 + mt * 16 + quad * 4 + r;
        out[(size_t)gm * 1024 + gn] = acc[mt][nt][r] + bv;
      }
    }
  }
}

extern "C" void kernel_launch(void* const* d_in, const int* in_sizes, int n_in,
                              void* d_out, int out_size, void* d_ws, size_t ws_size,
                              hipStream_t stream) {
  (void)in_sizes; (void)n_in; (void)out_size; (void)ws_size;
  const float* X     = (const float*)d_in[0];  // [4,2048,1024]
  const float* W_qkv = (const float*)d_in[1];  // [1024,3072]
  const float* W_out = (const float*)d_in[2];  // [1024,1024]
  const float* b_out = (const float*)d_in[3];  // [1024]
  float* out = (float*)d_out;                  // [4,2048,1024] fp32

  char* ws = (char*)d_ws;
  bf16_t* Xb    = (bf16_t*)(ws);               // 16 MB (dead after gemm_qkv)
  bf16_t* Wqkvt = (bf16_t*)(ws + 16777216);    // 6 MB  (dead after gemm_qkv)
  bf16_t* Woutt = (bf16_t*)(ws + 23068672);    // 2 MB
  bf16_t* Qb    = (bf16_t*)(ws + 25165824);    // 16 MB [b,h,s,d]
  bf16_t* Kb    = (bf16_t*)(ws + 41943040);    // 16 MB [b,h,s,d]
  bf16_t* Vt    = (bf16_t*)(ws + 58720256);    // 16 MB [b,h,d,s]
  bf16_t* ctx   = (bf16_t*)(ws + 75497472);    // 16 MB [b,s,1024]
  // attn split-K partials (no-max softmax -> exact additive combine):
  float* PA = (float*)(ws);                    // 16 MB, aliases dead Xb
  float* LA = (float*)(ws + 16777216);         // 256 KB, aliases dead Wqkvt
  float* LB = (float*)(ws + 17039360);         // 256 KB, aliases dead Wqkvt
  float* PB = (float*)(ws + 92274688);         // 16 MB tail (ws end ~109.1 MB)

  prep_kernel<<<12288, 256, 0, stream>>>(X, Xb, W_qkv, Wqkvt, W_out, Woutt);
  gemm_qkv_kernel<<<1536, 256, 0, stream>>>(Xb, Wqkvt, Qb, Kb, Vt);
  attn_kernel<<<dim3(1024), 256, 0, stream>>>(Qb, Kb, Vt, ctx, PA, PB, LA, LB);
  attn_norm_kernel<<<512, 256, 0, stream>>>(PA, PB, LA, LB, ctx);
  gemm_out_kernel<<<512, 256, 0, stream>>>(ctx, Woutt, b_out, out);
}

// Round 14
// 270.658 us; speedup vs baseline: 2.2990x; 2.2990x over previous
//
#include <hip/hip_runtime.h>
#include <hip/hip_bf16.h>

typedef __bf16 bf16_t;
typedef __bf16 bf16x8 __attribute__((ext_vector_type(8)));
typedef __bf16 bf16x4 __attribute__((ext_vector_type(4)));
typedef float f32x4 __attribute__((ext_vector_type(4)));
typedef float f32x16 __attribute__((ext_vector_type(16)));
typedef unsigned int u32x4 __attribute__((ext_vector_type(4)));

#define AS1(p) ((const __attribute__((address_space(1))) void*)(p))
#define AS3(p) ((__attribute__((address_space(3))) void*)(p))

// scale = HEAD_DIM^-0.5 * log2(e), folded into Q at QKV-GEMM epilogue
#define QSCALE 0.1803368801111204f

// ---------------- fused prep: cast X + transpose/cast both W (one launch) ----------------
__global__ __launch_bounds__(256) void prep_kernel(
    const float* __restrict__ X, bf16_t* __restrict__ Xb,
    const float* __restrict__ Wqkv, bf16_t* __restrict__ Wqkvt,
    const float* __restrict__ Wout, bf16_t* __restrict__ Woutt) {
  __shared__ float tile[32][33];
  int bid = blockIdx.x;
  if (bid < 8192) {
    int i = (bid * 256 + threadIdx.x) * 4;
    float4 v = *(const float4*)(X + i);
    bf16x4 o;
    o[0] = (bf16_t)v.x; o[1] = (bf16_t)v.y; o[2] = (bf16_t)v.z; o[3] = (bf16_t)v.w;
    *(bf16x4*)(Xb + i) = o;
    return;
  }
  bid -= 8192;
  const float* W; bf16_t* Wt; int N, bx, by;
  if (bid < 3072) { W = Wqkv; Wt = Wqkvt; N = 3072; bx = bid % 96; by = bid / 96; }
  else { bid -= 3072; W = Wout; Wt = Woutt; N = 1024; bx = bid & 31; by = bid >> 5; }
  const int K = 1024;
  int tx = threadIdx.x & 31, ty = threadIdx.x >> 5;
  int n0 = bx * 32, k0 = by * 32;
  for (int r = ty; r < 32; r += 8)
    tile[r][tx] = W[(size_t)(k0 + r) * N + n0 + tx];
  __syncthreads();
  for (int r = ty; r < 32; r += 8)
    Wt[(size_t)(n0 + r) * K + k0 + tx] = (bf16_t)tile[tx][r];
}

// ---------------- QKV GEMM: C[8192,3072] = Xb[8192,1024] @ Wt[3072,1024]^T ----------------
// BK=64, swizzled staging (rule #21), XCD-band swizzle. r12-measured structure.
__global__ __launch_bounds__(256) void gemm_qkv_kernel(
    const bf16_t* __restrict__ A, const bf16_t* __restrict__ Bt,
    bf16_t* __restrict__ Qb, bf16_t* __restrict__ Kb, bf16_t* __restrict__ Vt) {
  __shared__ __align__(16) bf16_t As[128 * 64];
  __shared__ __align__(16) bf16_t Bs[128 * 64];
  const int tid = threadIdx.x;
  const int lane = tid & 63, wave = tid >> 6;
  const int quad = lane >> 4, l15 = lane & 15;
  const int wr = wave >> 1, wc = wave & 1;
  const int bid = blockIdx.x;
  const int mt_ = (bid & 7) * 8 + ((bid >> 3) & 7);  // m-tile 0..63
  const int nt_ = bid >> 6;                          // n-tile 0..23
  const int m0 = mt_ * 128, n0 = nt_ * 128;
  f32x4 acc[4][4];
  const f32x4 vzero = {0.f, 0.f, 0.f, 0.f};
#pragma unroll
  for (int i = 0; i < 4; i++)
#pragma unroll
    for (int j = 0; j < 4; j++) acc[i][j] = vzero;

  for (int kb = 0; kb < 1024; kb += 64) {
    __syncthreads();
#pragma unroll
    for (int i = 0; i < 4; i++) {
      int slot = i * 256 + tid;                 // 1024 slots x 16B = 128 rows x 64 k
      int row = slot >> 3, ch = slot & 7;
      int gch = ch ^ (row & 7);                 // pre-swizzled global chunk
      __builtin_amdgcn_global_load_lds(AS1(A + (size_t)(m0 + row) * 1024 + kb + gch * 8),
                                       AS3(As + slot * 8), 16, 0, 0);
    }
#pragma unroll
    for (int i = 0; i < 4; i++) {
      int slot = i * 256 + tid;
      int row = slot >> 3, ch = slot & 7;
      int gch = ch ^ (row & 7);
      __builtin_amdgcn_global_load_lds(AS1(Bt + (size_t)(n0 + row) * 1024 + kb + gch * 8),
                                       AS3(Bs + slot * 8), 16, 0, 0);
    }
    __builtin_amdgcn_s_waitcnt(0);
    __syncthreads();
#pragma unroll
    for (int ks = 0; ks < 2; ks++) {            // two 32-wide K-substeps
      bf16x8 af[4], bfr[4];
#pragma unroll
      for (int t = 0; t < 4; t++) {
        int ra = wr * 64 + t * 16 + l15;
        af[t]  = *(const bf16x8*)(As + ra * 64 + ((ks * 4 + quad) ^ (ra & 7)) * 8);
        int rb = wc * 64 + t * 16 + l15;
        bfr[t] = *(const bf16x8*)(Bs + rb * 64 + ((ks * 4 + quad) ^ (rb & 7)) * 8);
      }
#pragma unroll
      for (int mt = 0; mt < 4; mt++)
#pragma unroll
        for (int nt = 0; nt < 4; nt++)
          acc[mt][nt] = __builtin_amdgcn_mfma_f32_16x16x32_bf16(af[mt], bfr[nt], acc[mt][nt], 0, 0, 0);
    }
  }
  // C layout: col=lane&15, row=quad*4+reg
#pragma unroll
  for (int nt = 0; nt < 4; nt++) {
    int gn = n0 + wc * 64 + nt * 16 + l15;
    int which = gn >> 10;   // 0=Q, 1=K, 2=V (uniform across lanes per nt)
    int rem = gn & 1023;
    int hh = rem >> 6, dd = rem & 63;
    if (which == 2) {
      // V transposed: Vt[b][h][dd][s], r-dim is consecutive s -> 8B vector store
#pragma unroll
      for (int mt = 0; mt < 4; mt++) {
        int gm0 = m0 + wr * 64 + mt * 16 + quad * 4;
        int b = gm0 >> 11, s = gm0 & 2047;
        bf16x4 o;
#pragma unroll
        for (int r = 0; r < 4; r++) o[r] = (bf16_t)acc[mt][nt][r];
        *(bf16x4*)(Vt + ((size_t)((b << 4) + hh) * 64 + dd) * 2048 + s) = o;
      }
    } else {
      bf16_t* dst = (which == 0) ? Qb : Kb;
      float scl = (which == 0) ? QSCALE : 1.0f;
#pragma unroll
      for (int mt = 0; mt < 4; mt++) {
#pragma unroll
        for (int r = 0; r < 4; r++) {
          int gm = m0 + wr * 64 + mt * 16 + quad * 4 + r;
          int b = gm >> 11, s = gm & 2047;
          dst[((size_t)((b << 4) + hh) * 2048 + s) * 64 + dd] = (bf16_t)(acc[mt][nt][r] * scl);
        }
      }
    }
  }
}

// pack two f32 into one u32 of 2 bf16
__device__ inline unsigned pack_bf16x2(float a, float b) {
  unsigned short lo = __builtin_bit_cast(unsigned short, (bf16_t)a);
  unsigned short hi = __builtin_bit_cast(unsigned short, (bf16_t)b);
  return (unsigned)lo | ((unsigned)hi << 16);
}

// ---------------- Flash attention, causal, split-K uniform blocks (r13 plan, no spill) ---
// r13's mid-loop conditional epilogue spilled Oacc (WRITE 1.17 GB). This version keeps
// the SAME uniform-length split (block A: tile p full + tile-P prefix [0,mA); block B:
// tile-P suffix [mA, 2Pq+2)) but as SEQUENTIAL r8-shaped loops — no conditional
// epilogue inside any loop, each region register-shaped like the proven 60-VGPR r8.
// No-max exp2 softmax => partials combine exactly by addition (attn_norm).
__global__ __launch_bounds__(256, 4) void attn_kernel(
    const bf16_t* __restrict__ Qg_, const bf16_t* __restrict__ Kg_,
    const bf16_t* __restrict__ Vtg_, bf16_t* __restrict__ ctx,
    float* __restrict__ PA, float* __restrict__ PB,
    float* __restrict__ LA, float* __restrict__ LB) {
  __shared__ __align__(16) bf16_t Ksm[2][64 * 64];
  __shared__ __align__(16) bf16_t Vsm[2][64 * 64];
  __shared__ float Lsh[128];
  const int tid = threadIdx.x;
  const int lane = tid & 63, w = tid >> 6;
  const int l31 = lane & 31, hl = lane >> 5;
  const int krow = (l31 & 0x13) | ((l31 & 4) << 1) | ((l31 & 8) >> 1);

  const int bh = blockIdx.x & 63;            // low bits -> XCD = bh%8
  const int pp = (blockIdx.x >> 6) & 7;      // pair index
  const int ab = blockIdx.x >> 9;            // 0=A, 1=B
  const int p = pp, Pq = 15 - pp;
  const int Jp = 2 * (p + 1);                // iters of tile p
  const int mA = 15 - 2 * p;                 // A's mask-free prefix length on tile P
  const int b = bh >> 4, h = bh & 15;
  const size_t base = (size_t)bh * 2048 * 64;
  const bf16_t* Qg = Qg_ + base;
  const bf16_t* Kg = Kg_ + base;
  const bf16_t* Vtg = Vtg_ + base;           // [d][s]

  int kadr[4];
#pragma unroll
  for (int kk = 0; kk < 4; kk++)
    kadr[kk] = (krow * 8 + ((kk * 2 + hl) ^ (krow & 7))) * 8;
  int vadr[2];
#pragma unroll
  for (int nv = 0; nv < 2; nv++) {
    const int dr = nv * 32 + l31;
    vadr[nv] = (dr * 8 + (hl ^ (dr & 7))) * 8;
  }

  auto stage_kv = [&](int bb, int jn) {
#pragma unroll
    for (int i = 0; i < 2; i++) {
      int slot = i * 256 + tid;
      int row = slot >> 3, c = (slot & 7) ^ (row & 7);
      __builtin_amdgcn_global_load_lds(AS1(Kg + ((size_t)jn * 64 + row) * 64 + c * 8),
                                       AS3(&Ksm[bb][0] + slot * 8), 16, 0, 0);
    }
#pragma unroll
    for (int i = 0; i < 2; i++) {
      int slot = i * 256 + tid;
      int d = slot >> 3, c = (slot & 7) ^ (d & 7);
      __builtin_amdgcn_global_load_lds(AS1(Vtg + (size_t)d * 2048 + jn * 64 + c * 8),
                                       AS3(&Vsm[bb][0] + slot * 8), 16, 0, 0);
    }
  };

  f32x16 zc;
#pragma unroll
  for (int e = 0; e < 16; e++) zc[e] = 0.f;

  const int tix = bh * 8 + pp;
  float* Pp = (ab ? PB : PA) + (size_t)tix * (128 * 64);
  float* Lp = (ab ? LB : LA) + tix * 128;

  bf16x8 aq[4];
  f32x16 Oacc[2];
#pragma unroll
  for (int e = 0; e < 16; e++) { Oacc[0][e] = 0.f; Oacc[1][e] = 0.f; }
  float Lpart = 0.f;
  int cur = 0;

  // r8-shaped inner body (straight-line, no conditional epilogue in any loop)
  auto nt_body = [&](const bf16_t* Kb, const bf16_t* Vb, int nt, bool masked) {
    __builtin_amdgcn_s_setprio(1);
    bf16x8 a0 = *(const bf16x8*)(Kb + nt * 2048 + kadr[0]);
    bf16x8 a1 = *(const bf16x8*)(Kb + nt * 2048 + kadr[1]);
    f32x16 sa = __builtin_amdgcn_mfma_f32_32x32x16_bf16(a0, aq[0], zc, 0, 0, 0);
    f32x16 sb = __builtin_amdgcn_mfma_f32_32x32x16_bf16(a1, aq[1], zc, 0, 0, 0);
    bf16x8 a2 = *(const bf16x8*)(Kb + nt * 2048 + kadr[2]);
    bf16x8 a3 = *(const bf16x8*)(Kb + nt * 2048 + kadr[3]);
    sa = __builtin_amdgcn_mfma_f32_32x32x16_bf16(a2, aq[2], sa, 0, 0, 0);
    sb = __builtin_amdgcn_mfma_f32_32x32x16_bf16(a3, aq[3], sb, 0, 0, 0);
    __builtin_amdgcn_s_setprio(0);

    float p16[16];
#pragma unroll
    for (int r = 0; r < 16; r++) {
      const int koff = hl * 8 + (r & 7) + 16 * (r >> 3);
      const float x = sa[r] + sb[r];
      p16[r] = (masked && (koff > l31)) ? 0.f : __builtin_exp2f(x);
    }
    {
      float a0s = p16[0] + p16[1], a1s = p16[2] + p16[3];
      float a2s = p16[4] + p16[5], a3s = p16[6] + p16[7];
      float a4s = p16[8] + p16[9], a5s = p16[10] + p16[11];
      float a6s = p16[12] + p16[13], a7s = p16[14] + p16[15];
      Lpart += ((a0s + a1s) + (a2s + a3s)) + ((a4s + a5s) + (a6s + a7s));
    }
    u32x4 w0, w1;
    w0[0] = pack_bf16x2(p16[0], p16[1]);   w0[1] = pack_bf16x2(p16[2], p16[3]);
    w0[2] = pack_bf16x2(p16[4], p16[5]);   w0[3] = pack_bf16x2(p16[6], p16[7]);
    w1[0] = pack_bf16x2(p16[8], p16[9]);   w1[1] = pack_bf16x2(p16[10], p16[11]);
    w1[2] = pack_bf16x2(p16[12], p16[13]); w1[3] = pack_bf16x2(p16[14], p16[15]);
    bf16x8 pa0 = __builtin_bit_cast(bf16x8, w0);
    bf16x8 pa1 = __builtin_bit_cast(bf16x8, w1);

    __builtin_amdgcn_s_setprio(1);
#pragma unroll
    for (int nv = 0; nv < 2; nv++) {
      bf16x8 bv0 = *(const bf16x8*)(Vb + (vadr[nv] ^ ((nt * 4 + 0) * 8)));
      Oacc[nv] = __builtin_amdgcn_mfma_f32_32x32x16_bf16(pa0, bv0, Oacc[nv], 0, 0, 0);
      bf16x8 bv1 = *(const bf16x8*)(Vb + (vadr[nv] ^ ((nt * 4 + 2) * 8)));
      Oacc[nv] = __builtin_amdgcn_mfma_f32_32x32x16_bf16(pa1, bv1, Oacc[nv], 0, 0, 0);
    }
    __builtin_amdgcn_s_setprio(0);
  };

  auto load_aq = [&](int qb_) {
    const int qgl = qb_ * 128 + w * 32 + l31;
#pragma unroll
    for (int kk = 0; kk < 4; kk++)
      aq[kk] = *(const bf16x8*)(Qg + (size_t)qgl * 64 + kk * 16 + hl * 8);
  };

  if (ab == 0) {
    // ---- phase 1: tile p, j in [0, Jp) — exactly the r8 loop ----
    load_aq(p);
    const int qrel = p * 128 + w * 32;
    stage_kv(0, 0);
    for (int j = 0; j < Jp; j++) {
      asm volatile("s_waitcnt vmcnt(0)" ::: "memory");
      __syncthreads();
      if (j + 1 < Jp) stage_kv(cur ^ 1, j + 1);
      else stage_kv(cur ^ 1, 0);                 // prefetch tile-P iter 0 (mA >= 1)
      const bf16_t* Kb = &Ksm[cur][0];
      const bf16_t* Vb = &Vsm[cur][0];
      const int k0 = j * 64;
#pragma unroll
      for (int nt = 0; nt < 2; nt++) {
        const int kk0 = k0 + nt * 32;
        if (kk0 <= qrel) nt_body(Kb, Vb, nt, kk0 == qrel);
      }
      cur ^= 1;
    }
    // direct ctx epilogue for tile p
    {
      float Lf = Lpart + __shfl_xor(Lpart, 32, 64);
      if (hl == 0) Lsh[w * 32 + l31] = Lf;
      asm volatile("s_waitcnt lgkmcnt(0)" ::: "memory");
#pragma unroll
      for (int r = 0; r < 16; r++) {
        const int crow = (r & 3) + 8 * (r >> 2) + 4 * hl;
        const float rl = __builtin_amdgcn_rcpf(Lsh[w * 32 + crow]);
        const int qrow = p * 128 + w * 32 + crow;
#pragma unroll
        for (int nv = 0; nv < 2; nv++)
          ctx[((size_t)b * 2048 + qrow) * 1024 + h * 64 + nv * 32 + l31] =
              (bf16_t)(Oacc[nv][r] * rl);
      }
    }
    // ---- phase 2: tile-P prefix, j in [0, mA) — never masked ----
#pragma unroll
    for (int e = 0; e < 16; e++) { Oacc[0][e] = 0.f; Oacc[1][e] = 0.f; }
    Lpart = 0.f;
    load_aq(Pq);
    for (int j = 0; j < mA; j++) {
      asm volatile("s_waitcnt vmcnt(0)" ::: "memory");
      __syncthreads();
      if (j + 1 < mA) stage_kv(cur ^ 1, j + 1);
      const bf16_t* Kb = &Ksm[cur][0];
      const bf16_t* Vb = &Vsm[cur][0];
      nt_body(Kb, Vb, 0, false);
      nt_body(Kb, Vb, 1, false);
      cur ^= 1;
    }
  } else {
    // ---- block B: tile-P suffix, j in [mA, mA+17) — r8 loop with offset ----
    load_aq(Pq);
    const int qrel = Pq * 128 + w * 32;
    stage_kv(0, mA);
    for (int i = 0; i < 17; i++) {
      asm volatile("s_waitcnt vmcnt(0)" ::: "memory");
      __syncthreads();
      if (i + 1 < 17) stage_kv(cur ^ 1, mA + i + 1);
      const bf16_t* Kb = &Ksm[cur][0];
      const bf16_t* Vb = &Vsm[cur][0];
      const int k0 = (mA + i) * 64;
#pragma unroll
      for (int nt = 0; nt < 2; nt++) {
        const int kk0 = k0 + nt * 32;
        if (kk0 <= qrel) nt_body(Kb, Vb, nt, kk0 == qrel);
      }
      cur ^= 1;
    }
  }

  // partial write for tile P (A: prefix sums; B: suffix sums)
  {
    float Lf = Lpart + __shfl_xor(Lpart, 32, 64);
    if (hl == 0) Lp[w * 32 + l31] = Lf;
#pragma unroll
    for (int r = 0; r < 16; r++) {
      const int crow = (r & 3) + 8 * (r >> 2) + 4 * hl;
      const int row = w * 32 + crow;
#pragma unroll
      for (int nv = 0; nv < 2; nv++)
        Pp[row * 64 + nv * 32 + l31] = Oacc[nv][r];
    }
  }
}

// ---------------- combine partials -> ctx upper tiles ----------------
__global__ __launch_bounds__(256) void attn_norm_kernel(
    const float* __restrict__ PA, const float* __restrict__ PB,
    const float* __restrict__ LA, const float* __restrict__ LB,
    bf16_t* __restrict__ ctx) {
  const int t = blockIdx.x;            // 0..511 = bh*8 + pp
  const int bh = t >> 3, pp = t & 7;
  const int Pq = 15 - pp;
  const int b = bh >> 4, h = bh & 15;
  const float4* pa = (const float4*)(PA + (size_t)t * 8192);
  const float4* pb = (const float4*)(PB + (size_t)t * 8192);
  const float* la = LA + t * 128;
  const float* lb = LB + t * 128;
#pragma unroll
  for (int k = 0; k < 8; k++) {
    const int v = threadIdx.x + k * 256;   // 0..2047 float4 index (16 per row)
    const int row = v >> 4, dd = (v & 15) * 4;
    float4 a = pa[v], c = pb[v];
    const float rl = __builtin_amdgcn_rcpf(la[row] + lb[row]);
    bf16x4 o;
    o[0] = (bf16_t)((a.x + c.x) * rl);
    o[1] = (bf16_t)((a.y + c.y) * rl);
    o[2] = (bf16_t)((a.z + c.z) * rl);
    o[3] = (bf16_t)((a.w + c.w) * rl);
    *(bf16x4*)(ctx + ((size_t)b * 2048 + Pq * 128 + row) * 1024 + h * 64 + dd) = o;
  }
}

// ---------------- out proj: out[8192,1024] = ctx @ Wout^T + b ----------------
__global__ __launch_bounds__(256) void gemm_out_kernel(
    const bf16_t* __restrict__ A, const bf16_t* __restrict__ Bt,
    const float* __restrict__ bias, float* __restrict__ out) {
  __shared__ __align__(16) bf16_t As[128 * 64];
  __shared__ __align__(16) bf16_t Bs[128 * 64];
  const int tid = threadIdx.x;
  const int lane = tid & 63, wave = tid >> 6;
  const int quad = lane >> 4, l15 = lane & 15;
  const int wr = wave >> 1, wc = wave & 1;
  const int bid = blockIdx.x;
  const int mt_ = (bid & 7) * 8 + ((bid >> 3) & 7);  // m-tile 0..63
  const int nt_ = bid >> 6;                          // n-tile 0..7
  const int m0 = mt_ * 128, n0 = nt_ * 128;
  f32x4 acc[4][4];
  const f32x4 vzero = {0.f, 0.f, 0.f, 0.f};
#pragma unroll
  for (int i = 0; i < 4; i++)
#pragma unroll
    for (int j = 0; j < 4; j++) acc[i][j] = vzero;

  for (int kb = 0; kb < 1024; kb += 64) {
    __syncthreads();
#pragma unroll
    for (int i = 0; i < 4; i++) {
      int slot = i * 256 + tid;
      int row = slot >> 3, ch = slot & 7;
      int gch = ch ^ (row & 7);
      __builtin_amdgcn_global_load_lds(AS1(A + (size_t)(m0 + row) * 1024 + kb + gch * 8),
                                       AS3(As + slot * 8), 16, 0, 0);
    }
#pragma unroll
    for (int i = 0; i < 4; i++) {
      int slot = i * 256 + tid;
      int row = slot >> 3, ch = slot & 7;
      int gch = ch ^ (row & 7);
      __builtin_amdgcn_global_load_lds(AS1(Bt + (size_t)(n0 + row) * 1024 + kb + gch * 8),
                                       AS3(Bs + slot * 8), 16, 0, 0);
    }
    __builtin_amdgcn_s_waitcnt(0);
    __syncthreads();
#pragma unroll
    for (int ks = 0; ks < 2; ks++) {
      bf16x8 af[4], bfr[4];
#pragma unroll
      for (int t = 0; t < 4; t++) {
        int ra = wr * 64 + t * 16 + l15;
        af[t]  = *(const bf16x8*)(As + ra * 64 + ((ks * 4 + quad) ^ (ra & 7)) * 8);
        int rb = wc * 64 + t * 16 + l15;
        bfr[t] = *(const bf16x8*)(Bs + rb * 64 + ((ks * 4 + quad) ^ (rb & 7)) * 8);
      }
#pragma unroll
      for (int mt = 0; mt < 4; mt++)
#pragma unroll
        for (int nt = 0; nt < 4; nt++)
          acc[mt][nt] = __builtin_amdgcn_mfma_f32_16x16x32_bf16(af[mt], bfr[nt], acc[mt][nt], 0, 0, 0);
    }
  }
#pragma unroll
  for (int nt = 0; nt < 4; nt++) {
    int gn = n0 + wc * 64 + nt * 16 + l15;
    float bv = bias[gn];
#pragma unroll
    for (int mt = 0; mt < 4; mt++) {
#pragma unroll
      for (int r = 0; r < 4; r++) {
        int gm = m0 + wr * 64 + mt * 16 + quad * 4 + r;
        out[(size_t)gm * 1024 + gn] = acc[mt][nt][r] + bv;
      }
    }
  }
}

extern "C" void kernel_launch(void* const* d_in, const int* in_sizes, int n_in,
                              void* d_out, int out_size, void* d_ws, size_t ws_size,
                              hipStream_t stream) {
  (void)in_sizes; (void)n_in; (void)out_size; (void)ws_size;
  const float* X     = (const float*)d_in[0];  // [4,2048,1024]
  const float* W_qkv = (const float*)d_in[1];  // [1024,3072]
  const float* W_out = (const float*)d_in[2];  // [1024,1024]
  const float* b_out = (const float*)d_in[3];  // [1024]
  float* out = (float*)d_out;                  // [4,2048,1024] fp32

  char* ws = (char*)d_ws;
  bf16_t* Xb    = (bf16_t*)(ws);               // 16 MB (dead after gemm_qkv)
  bf16_t* Wqkvt = (bf16_t*)(ws + 16777216);    // 6 MB  (dead after gemm_qkv)
  bf16_t* Woutt = (bf16_t*)(ws + 23068672);    // 2 MB
  bf16_t* Qb    = (bf16_t*)(ws + 25165824);    // 16 MB [b,h,s,d]
  bf16_t* Kb    = (bf16_t*)(ws + 41943040);    // 16 MB [b,h,s,d]
  bf16_t* Vt    = (bf16_t*)(ws + 58720256);    // 16 MB [b,h,d,s]
  bf16_t* ctx   = (bf16_t*)(ws + 75497472);    // 16 MB [b,s,1024]
  // attn split-K partials (no-max softmax -> exact additive combine):
  float* PA = (float*)(ws);                    // 16 MB, aliases dead Xb
  float* LA = (float*)(ws + 16777216);         // 256 KB, aliases dead Wqkvt
  float* LB = (float*)(ws + 17039360);         // 256 KB, aliases dead Wqkvt
  float* PB = (float*)(ws + 92274688);         // 16 MB tail

  prep_kernel<<<12288, 256, 0, stream>>>(X, Xb, W_qkv, Wqkvt, W_out, Woutt);
  gemm_qkv_kernel<<<1536, 256, 0, stream>>>(Xb, Wqkvt, Qb, Kb, Vt);
  attn_kernel<<<dim3(1024), 256, 0, stream>>>(Qb, Kb, Vt, ctx, PA, PB, LA, LB);
  attn_norm_kernel<<<512, 256, 0, stream>>>(PA, PB, LA, LB, ctx);
  gemm_out_kernel<<<512, 256, 0, stream>>>(ctx, Woutt, b_out, out);
}